// Round 12
// baseline (74.264 us; speedup 1.0000x reference)
//
#include <hip/hip_runtime.h>
#include <math.h>

namespace {
constexpr int RADIUS = 9;
constexpr float EPSV = 1e-5f;
constexpr int N_ = 2, C_ = 64, H_ = 128, W_ = 192;
constexpr int HW  = H_ * W_;            // 24576
constexpr int CHW = C_ * HW;
constexpr size_t OUT1 = (size_t)N_ * 81 * HW;

constexpr int XT = 64, YT = 4;          // spatial tile; i fully in grid.z
constexpr int NT = 512;                 // 8 waves; wave = channel-group of 8
constexpr int NW = 8;
constexpr int ROUNDS = 8;               // 1 channel / wave / round
constexpr int MROWS = 4;                // map halo rows (= YT)
constexpr int NCH = 19;                 // 16B chunks per map row
constexpr int MCOLS = 76;               // floats per map row (x0-12 .. x0+63)
constexpr int MAP_SLOTS = MROWS * NCH;  // 76
constexpr int HBUF = 768;               // floats/buffer: 512 map(+pad) + 256 img
constexpr int OFF_IMG = 512;
constexpr int WBUF = 2 * HBUF;          // 1536 floats per wave (dbuf)
constexpr int OFF_INVM = NW * WBUF;     // 12288
constexpr int LDS_F = OFF_INVM + MROWS * MCOLS;   // 12592 floats = 50368 B
}

__device__ __forceinline__ void load_lds16(const float* g, float* l) {
    __builtin_amdgcn_global_load_lds(
        (const __attribute__((address_space(1))) unsigned int*)(const void*)g,
        (__attribute__((address_space(3))) unsigned int*)(void*)l,
        16, 0, 0);
}

// ---------------------------------------------------------------------------
// Kernel 1: invM (map channel-norms) + left-edge replicate strip. 8-way c-split.
// ---------------------------------------------------------------------------
__global__ __launch_bounds__(64)
void norms_kernel(const float* __restrict__ mp,
                  float* __restrict__ invM,
                  float* __restrict__ strip) {
    __shared__ float4 sM[8][8];
    const int tid = threadIdx.x;
    const int cg = tid >> 3;
    const int s  = tid & 7;
    const int q4 = blockIdx.x * 8 + s;
    const int n = q4 / (HW / 4);
    const int pix = (q4 - n * (HW / 4)) * 4;
    const int y = pix / W_;
    const int x = pix - y * W_;
    const float* pm = mp + (size_t)n * CHW + pix;
    const bool e = (x == 0);
    float* sp = strip + ((size_t)(n * C_ + cg * 8) * H_ + y) * 4;

    float4 sm = {0.f, 0.f, 0.f, 0.f};
#pragma unroll
    for (int cc = 0; cc < 8; ++cc) {
        float4 b = *(const float4*)(pm + (size_t)(cg * 8 + cc) * HW);
        sm.x = fmaf(b.x, b.x, sm.x); sm.y = fmaf(b.y, b.y, sm.y);
        sm.z = fmaf(b.z, b.z, sm.z); sm.w = fmaf(b.w, b.w, sm.w);
        if (e) { float4 v = {b.x, b.x, b.x, b.x}; *(float4*)(sp + (size_t)cc * H_ * 4) = v; }
    }
    sM[cg][s] = sm;
    __syncthreads();
    if (tid < 8) {
        float4 b = sM[0][tid];
#pragma unroll
        for (int g = 1; g < 8; ++g) {
            float4 v = sM[g][tid];
            b.x += v.x; b.y += v.y; b.z += v.z; b.w += v.w;
        }
        float4 vm;
        vm.x = 1.f / (sqrtf(b.x) + EPSV); vm.y = 1.f / (sqrtf(b.y) + EPSV);
        vm.z = 1.f / (sqrtf(b.z) + EPSV); vm.w = 1.f / (sqrtf(b.w) + EPSV);
        *(float4*)(invM + (size_t)n * HW + pix) = vm;
    }
}

// ---------------------------------------------------------------------------
// Kernel 2: raw correlation + inline img-norm. Wave-private dbuf staging via
// global_load_lds; per-round: issue DMA(ri+1) -> compute(ri) -> __syncthreads
// (compiler drains vmcnt at the barrier -> proven-correct R8/R10 mechanism).
//   dotRaw[p,(i,j)] = sum_c map[c, clamp(p+(i,j)-9)] * img[c, p]
//   out_diss = invI[p]*dotRaw ;  out_cos = 1 - invM[p']*out_diss
// ---------------------------------------------------------------------------
__global__ __launch_bounds__(NT)
void corr_kernel(const float* __restrict__ img,
                 const float* __restrict__ mp,
                 const float* __restrict__ invMg,
                 const float* __restrict__ strip,
                 float* __restrict__ out) {
    __shared__ float smem[LDS_F];

    const int bz = blockIdx.z;             // n*9 + i
    const int n    = bz / RADIUS;
    const int iOff = bz - n * RADIUS;
    const int y0 = blockIdx.y * YT;
    const int x0 = blockIdx.x * XT;
    const int tid = threadIdx.x;
    const int w    = tid >> 6;             // wave = channel group (8 ch)
    const int lane = tid & 63;
    const int ty = lane >> 4;              // 0..3
    const int xc = lane & 15;              // 0..15
    const int ybase = y0 + iOff - RADIUS;
    const int ch0 = w * 8;

    const float* imgN = img + (size_t)n * CHW;
    const float* mapN = mp  + (size_t)n * CHW;

    // ---- invM halo (76 float4; epilogue-only) ----
    if (tid < MAP_SLOTS) {
        int r = tid / NCH, k = tid - r * NCH;
        int gy = min(max(ybase + r, 0), H_ - 1);
        int gxs = x0 - 12 + 4 * k;
        const float* src = invMg + n * HW + (size_t)gy * W_;
        float4 v;
        if (gxs >= 0) v = *(const float4*)(src + gxs);
        else { float s0 = src[0]; v.x = s0; v.y = s0; v.z = s0; v.w = s0; }
        *(float4*)&smem[OFF_INVM + r * MCOLS + 4 * k] = v;
    }

    // ---- per-lane DMA descriptors (round stride = 1 channel) ----
    const float *pA, *pB, *pI;
    int strA, strB;
    {   int s = lane;                      // map slots 0..63
        int r = s / NCH, k = s - NCH * r;
        int gy = min(max(ybase + r, 0), H_ - 1);
        int gxs = x0 - 12 + 4 * k;
        if (gxs < 0) { pA = strip + ((size_t)(n * C_ + ch0) * H_ + gy) * 4; strA = H_ * 4; }
        else         { pA = mapN + (size_t)ch0 * HW + (size_t)gy * W_ + gxs; strA = HW; }
    }
    {   int s = min(64 + lane, MAP_SLOTS - 1);   // map slots 64..75 (+pad dup)
        int r = s / NCH, k = s - NCH * r;
        int gy = min(max(ybase + r, 0), H_ - 1);
        int gxs = x0 - 12 + 4 * k;
        if (gxs < 0) { pB = strip + ((size_t)(n * C_ + ch0) * H_ + gy) * 4; strB = H_ * 4; }
        else         { pB = mapN + (size_t)ch0 * HW + (size_t)gy * W_ + gxs; strB = HW; }
    }
    pI = imgN + (size_t)ch0 * HW + (size_t)(y0 + ty) * W_ + x0 + 4 * xc;

    float* const wb = smem + w * WBUF;     // this wave's private buffers
    const int dA = 4 * lane;
    const int dB = 4 * (64 + lane);
    const int dI = OFF_IMG + 4 * lane;

    float acc[4][RADIUS];
#pragma unroll
    for (int p = 0; p < 4; ++p)
#pragma unroll
        for (int j = 0; j < RADIUS; ++j) acc[p][j] = 0.f;
    float si[4] = {0.f, 0.f, 0.f, 0.f};

    const int mapRd = ty * MCOLS + 4 * xc;

    // ---- prologue: round 0; barrier drains the DMA (and invM staging) ----
    load_lds16(pA, wb + dA);
    load_lds16(pB, wb + dB);
    load_lds16(pI, wb + dI);
    __syncthreads();

    // ---- main loop: issue(ri+1) -> compute(ri) -> barrier (drain ri+1) ----
#pragma unroll
    for (int ri = 0; ri < ROUNDS; ++ri) {
        if (ri + 1 < ROUNDS) {
            float* nb = wb + ((ri + 1) & 1) * HBUF;
            load_lds16(pA + (size_t)(ri + 1) * strA, nb + dA);
            load_lds16(pB + (size_t)(ri + 1) * strB, nb + dB);
            load_lds16(pI + (size_t)(ri + 1) * HW,   nb + dI);
        }
        const float* cur = wb + (ri & 1) * HBUF;
        const float* mb = cur + mapRd;
        float wreg[16];
        *(float4*)&wreg[0]  = *(const float4*)(mb);
        *(float4*)&wreg[4]  = *(const float4*)(mb + 4);
        *(float4*)&wreg[8]  = *(const float4*)(mb + 8);
        *(float4*)&wreg[12] = *(const float4*)(mb + 12);
        const float4 a4 = *(const float4*)(cur + OFF_IMG + 4 * lane);
        const float a[4] = {a4.x, a4.y, a4.z, a4.w};
        si[0] = fmaf(a[0], a[0], si[0]);
        si[1] = fmaf(a[1], a[1], si[1]);
        si[2] = fmaf(a[2], a[2], si[2]);
        si[3] = fmaf(a[3], a[3], si[3]);
#pragma unroll
        for (int p = 0; p < 4; ++p)
#pragma unroll
            for (int j = 0; j < RADIUS; ++j)
                acc[p][j] = fmaf(wreg[p + j + 3], a[p], acc[p][j]);
        __syncthreads();
    }

    // ==== epilogue: 8-way cross-wave reduce, SoA float4 layout ====
    const int slot = w * 64 + lane;        // 0..511
    // ---- half 1: j=0..3 + si ----
#pragma unroll
    for (int q = 0; q < 4; ++q) {
        float4 v = {acc[0][q], acc[1][q], acc[2][q], acc[3][q]};
        *(float4*)&smem[(q * 512 + slot) * 4] = v;
    }
    { float4 v = {si[0], si[1], si[2], si[3]}; *(float4*)&smem[(4 * 512 + slot) * 4] = v; }
    __syncthreads();
    // everyone: sum si across groups -> invI
    float4 sv = {0.f, 0.f, 0.f, 0.f};
#pragma unroll
    for (int g = 0; g < NW; ++g) {
        float4 v = *(const float4*)&smem[(4 * 512 + g * 64 + lane) * 4];
        sv.x += v.x; sv.y += v.y; sv.z += v.z; sv.w += v.w;
    }
    float4 vI;
    vI.x = 1.f / (sqrtf(sv.x) + EPSV);
    vI.y = 1.f / (sqrtf(sv.y) + EPSV);
    vI.z = 1.f / (sqrtf(sv.z) + EPSV);
    vI.w = 1.f / (sqrtf(sv.w) + EPSV);

    const int y  = y0 + ty;
    const int xb = x0 + 4 * xc;
    const float* wmRow = &smem[OFF_INVM + ty * MCOLS + 4 * xc + 3];
    float* ocB = out + (size_t)(n * 81 + iOff * RADIUS) * HW + (size_t)y * W_ + xb;

    if (w < 4) {                           // waves 0..3 store j = w
        const int j = w;
        float4 s = {0.f, 0.f, 0.f, 0.f};
#pragma unroll
        for (int g = 0; g < NW; ++g) {
            float4 v = *(const float4*)&smem[(j * 512 + g * 64 + lane) * 4];
            s.x += v.x; s.y += v.y; s.z += v.z; s.w += v.w;
        }
        float4 vd, vc;
        vd.x = s.x * vI.x; vd.y = s.y * vI.y; vd.z = s.z * vI.z; vd.w = s.w * vI.w;
        vc.x = 1.f - vd.x * wmRow[j + 0];
        vc.y = 1.f - vd.y * wmRow[j + 1];
        vc.z = 1.f - vd.z * wmRow[j + 2];
        vc.w = 1.f - vd.w * wmRow[j + 3];
        *(float4*)(ocB + (size_t)j * HW) = vc;
        *(float4*)(ocB + OUT1 + (size_t)j * HW) = vd;
    }
    __syncthreads();
    // ---- half 2: j=4..8 ----
#pragma unroll
    for (int q = 0; q < 5; ++q) {
        float4 v = {acc[0][q + 4], acc[1][q + 4], acc[2][q + 4], acc[3][q + 4]};
        *(float4*)&smem[(q * 512 + slot) * 4] = v;
    }
    __syncthreads();
    if (w >= 4) {                          // waves 4..7 store j = w
        const int j = w;
        float4 s = {0.f, 0.f, 0.f, 0.f};
#pragma unroll
        for (int g = 0; g < NW; ++g) {
            float4 v = *(const float4*)&smem[((j - 4) * 512 + g * 64 + lane) * 4];
            s.x += v.x; s.y += v.y; s.z += v.z; s.w += v.w;
        }
        float4 vd, vc;
        vd.x = s.x * vI.x; vd.y = s.y * vI.y; vd.z = s.z * vI.z; vd.w = s.w * vI.w;
        vc.x = 1.f - vd.x * wmRow[j + 0];
        vc.y = 1.f - vd.y * wmRow[j + 1];
        vc.z = 1.f - vd.z * wmRow[j + 2];
        vc.w = 1.f - vd.w * wmRow[j + 3];
        *(float4*)(ocB + (size_t)j * HW) = vc;
        *(float4*)(ocB + OUT1 + (size_t)j * HW) = vd;
    }
    if (w == 0) {                          // wave 0 also stores j = 8
        const int j = 8;
        float4 s = {0.f, 0.f, 0.f, 0.f};
#pragma unroll
        for (int g = 0; g < NW; ++g) {
            float4 v = *(const float4*)&smem[(4 * 512 + g * 64 + lane) * 4];
            s.x += v.x; s.y += v.y; s.z += v.z; s.w += v.w;
        }
        float4 vd, vc;
        vd.x = s.x * vI.x; vd.y = s.y * vI.y; vd.z = s.z * vI.z; vd.w = s.w * vI.w;
        vc.x = 1.f - vd.x * wmRow[j + 0];
        vc.y = 1.f - vd.y * wmRow[j + 1];
        vc.z = 1.f - vd.z * wmRow[j + 2];
        vc.w = 1.f - vd.w * wmRow[j + 3];
        *(float4*)(ocB + (size_t)j * HW) = vc;
        *(float4*)(ocB + OUT1 + (size_t)j * HW) = vd;
    }
}

extern "C" void kernel_launch(void* const* d_in, const int* in_sizes, int n_in,
                              void* d_out, int out_size, void* d_ws, size_t ws_size,
                              hipStream_t stream) {
    const float* img = (const float*)d_in[0];
    const float* mp  = (const float*)d_in[1];
    float* out   = (float*)d_out;
    float* invM  = (float*)d_ws;                  // N_*HW floats
    float* strip = invM + N_ * HW;                // N_*C_*H_*4 floats

    norms_kernel<<<(N_ * HW / 4) / 8, 64, 0, stream>>>(mp, invM, strip);

    dim3 grid(W_ / XT, H_ / YT, N_ * RADIUS);     // 3 x 32 x 18 = 1728 blocks
    corr_kernel<<<grid, NT, 0, stream>>>(img, mp, invM, strip, out);
}

// Round 14
// 53.331 us; speedup vs baseline: 1.3925x; 1.3925x over previous
//
#include <hip/hip_runtime.h>
#include <math.h>

namespace {
constexpr int RADIUS = 9;
constexpr float EPSV = 1e-5f;
constexpr int N_ = 2, C_ = 64, H_ = 128, W_ = 192;
constexpr int HW  = H_ * W_;            // 24576
constexpr int CHW = C_ * HW;
constexpr size_t OUT1 = (size_t)N_ * 81 * HW;

constexpr int XT = 64, YT = 4;          // spatial tile; i fully in grid.z
constexpr int NT = 512;                 // 8 waves; wave = channel-group of 8
constexpr int NW = 8;
constexpr int ROUNDS = 8;               // 1 channel / wave / round
constexpr int MROWS = 4;                // map halo rows (= YT)
constexpr int NCH = 19;                 // 16B chunks per map row
constexpr int MCOLS = 76;               // floats per map row (x0-12 .. x0+63)
constexpr int MAP_SLOTS = MROWS * NCH;  // 76
constexpr int HBUF = 512;               // floats/buffer: 128 slots (76 real + pad)
constexpr int WBUF = 2 * HBUF;          // 1024 floats per wave (dbuf)
constexpr int OFF_INVM = 10240;         // after epilogue-reduce overlay area
constexpr int LDS_F = OFF_INVM + MROWS * MCOLS;   // 10544 floats = 42176 B
}

// ---------------------------------------------------------------------------
// Kernel 1: invM (map channel-norms). 8-way c-split, 64-thread blocks.
// ---------------------------------------------------------------------------
__global__ __launch_bounds__(64)
void norms_kernel(const float* __restrict__ mp,
                  float* __restrict__ invM) {
    __shared__ float4 sM[8][8];
    const int tid = threadIdx.x;
    const int cg = tid >> 3;
    const int s  = tid & 7;
    const int q4 = blockIdx.x * 8 + s;
    const int n = q4 / (HW / 4);
    const int pix = (q4 - n * (HW / 4)) * 4;
    const float* pm = mp + (size_t)n * CHW + pix;

    float4 sm = {0.f, 0.f, 0.f, 0.f};
#pragma unroll
    for (int cc = 0; cc < 8; ++cc) {
        float4 b = *(const float4*)(pm + (size_t)(cg * 8 + cc) * HW);
        sm.x = fmaf(b.x, b.x, sm.x); sm.y = fmaf(b.y, b.y, sm.y);
        sm.z = fmaf(b.z, b.z, sm.z); sm.w = fmaf(b.w, b.w, sm.w);
    }
    sM[cg][s] = sm;
    __syncthreads();
    if (tid < 8) {
        float4 b = sM[0][tid];
#pragma unroll
        for (int g = 1; g < 8; ++g) {
            float4 v = sM[g][tid];
            b.x += v.x; b.y += v.y; b.z += v.z; b.w += v.w;
        }
        float4 vm;
        vm.x = 1.f / (sqrtf(b.x) + EPSV); vm.y = 1.f / (sqrtf(b.y) + EPSV);
        vm.z = 1.f / (sqrtf(b.z) + EPSV); vm.w = 1.f / (sqrtf(b.w) + EPSV);
        *(float4*)(invM + (size_t)n * HW + pix) = vm;
    }
}

// ---------------------------------------------------------------------------
// Kernel 2: raw correlation + inline img-norm. Wave-private dbuf map staging
// via REGISTERS + ds_write (T14 split: load(ri+1)->regs, compute(ri) from LDS,
// ds_write(ri+1)). No barriers, no manual waitcnt in the main loop —
// correctness enforced by compiler-tracked register/LDS dependencies.
//   dotRaw[p,(i,j)] = sum_c map[c, clamp(p+(i,j)-9)] * img[c, p]
//   out_diss = invI[p]*dotRaw ;  out_cos = 1 - invM[p']*out_diss
// ---------------------------------------------------------------------------
__global__ __launch_bounds__(NT)
void corr_kernel(const float* __restrict__ img,
                 const float* __restrict__ mp,
                 const float* __restrict__ invMg,
                 float* __restrict__ out) {
    __shared__ float smem[LDS_F];

    const int bz = blockIdx.z;             // n*9 + i
    const int n    = bz / RADIUS;
    const int iOff = bz - n * RADIUS;
    const int y0 = blockIdx.y * YT;
    const int x0 = blockIdx.x * XT;
    const int tid = threadIdx.x;
    const int w    = tid >> 6;             // wave = channel group (8 ch)
    const int lane = tid & 63;
    const int ty = lane >> 4;              // 0..3
    const int xc = lane & 15;              // 0..15
    const int ybase = y0 + iOff - RADIUS;
    const int ch0 = w * 8;

    const float* imgN = img + (size_t)n * CHW;
    const float* mapN = mp  + (size_t)n * CHW;

    // ---- invM halo (76 float4; epilogue-only, synced by epilogue barrier) ----
    if (tid < MAP_SLOTS) {
        int r = tid / NCH, k = tid - r * NCH;
        int gy = min(max(ybase + r, 0), H_ - 1);
        int gxs = x0 - 12 + 4 * k;
        const float* src = invMg + n * HW + (size_t)gy * W_;
        float4 v;
        if (gxs >= 0) v = *(const float4*)(src + gxs);
        else { float s0 = src[0]; v.x = s0; v.y = s0; v.z = s0; v.w = s0; }
        *(float4*)&smem[OFF_INVM + r * MCOLS + 4 * k] = v;
    }

    // ---- per-lane staging descriptors (round stride = 1 channel = HW) ----
    const float *pA, *pB, *pI;
    bool bcA, bcB;
    {   int s = lane;                      // map slots 0..63
        int r = s / NCH, k = s - NCH * r;
        int gy = min(max(ybase + r, 0), H_ - 1);
        int gxs = x0 - 12 + 4 * k;
        bcA = (gxs < 0); if (gxs < 0) gxs = 0;
        pA = mapN + (size_t)ch0 * HW + (size_t)gy * W_ + gxs;
    }
    {   int s = min(64 + lane, MAP_SLOTS - 1);   // map slots 64..75 (+dup)
        int r = s / NCH, k = s - NCH * r;
        int gy = min(max(ybase + r, 0), H_ - 1);
        int gxs = x0 - 12 + 4 * k;
        bcB = (gxs < 0); if (gxs < 0) gxs = 0;
        pB = mapN + (size_t)ch0 * HW + (size_t)gy * W_ + gxs;
    }
    pI = imgN + (size_t)ch0 * HW + (size_t)(y0 + ty) * W_ + x0 + 4 * xc;

    float* const wb = smem + w * WBUF;     // this wave's private dbuf
    const int dA = 4 * lane;               // [0,256)
    const int dB = 4 * (64 + lane);        // [256,512)

    float acc[4][RADIUS];
#pragma unroll
    for (int p = 0; p < 4; ++p)
#pragma unroll
        for (int j = 0; j < RADIUS; ++j) acc[p][j] = 0.f;
    float si[4] = {0.f, 0.f, 0.f, 0.f};

    const int mapRd = ty * MCOLS + 4 * xc;

    // ---- prologue: round 0 -> regs -> buf0; img0 -> reg ----
    float4 mA = *(const float4*)(pA);
    float4 mB = *(const float4*)(pB);
    float4 aI = *(const float4*)(pI);
    if (bcA) { mA.y = mA.x; mA.z = mA.x; mA.w = mA.x; }
    if (bcB) { mB.y = mB.x; mB.z = mB.x; mB.w = mB.x; }
    *(float4*)&wb[dA] = mA;
    *(float4*)&wb[dB] = mB;

    // ---- main loop: load(ri+1)->regs | compute(ri) | ds_write(ri+1) ----
#pragma unroll
    for (int ri = 0; ri < ROUNDS; ++ri) {
        float4 nA, nB, nI;
        if (ri + 1 < ROUNDS) {
            nA = *(const float4*)(pA + (size_t)(ri + 1) * HW);
            nB = *(const float4*)(pB + (size_t)(ri + 1) * HW);
            nI = *(const float4*)(pI + (size_t)(ri + 1) * HW);
        }
        const float* cur = wb + (ri & 1) * HBUF;
        const float* mb = cur + mapRd;
        float wreg[16];
        *(float4*)&wreg[0]  = *(const float4*)(mb);
        *(float4*)&wreg[4]  = *(const float4*)(mb + 4);
        *(float4*)&wreg[8]  = *(const float4*)(mb + 8);
        *(float4*)&wreg[12] = *(const float4*)(mb + 12);
        const float a[4] = {aI.x, aI.y, aI.z, aI.w};
        si[0] = fmaf(a[0], a[0], si[0]);
        si[1] = fmaf(a[1], a[1], si[1]);
        si[2] = fmaf(a[2], a[2], si[2]);
        si[3] = fmaf(a[3], a[3], si[3]);
#pragma unroll
        for (int p = 0; p < 4; ++p)
#pragma unroll
            for (int j = 0; j < RADIUS; ++j)
                acc[p][j] = fmaf(wreg[p + j + 3], a[p], acc[p][j]);
        if (ri + 1 < ROUNDS) {
            if (bcA) { nA.y = nA.x; nA.z = nA.x; nA.w = nA.x; }
            if (bcB) { nB.y = nB.x; nB.z = nB.x; nB.w = nB.x; }
            float* nb = wb + ((ri + 1) & 1) * HBUF;
            *(float4*)&nb[dA] = nA;
            *(float4*)&nb[dB] = nB;
            aI = nI;
        }
    }

    // ==== epilogue: 8-way cross-wave reduce, SoA float4 layout ====
    __syncthreads();                       // all waves done with buffers
    const int slot = w * 64 + lane;        // 0..511
    // ---- half 1: j=0..3 + si ----
#pragma unroll
    for (int q = 0; q < 4; ++q) {
        float4 v = {acc[0][q], acc[1][q], acc[2][q], acc[3][q]};
        *(float4*)&smem[(q * 512 + slot) * 4] = v;
    }
    { float4 v = {si[0], si[1], si[2], si[3]}; *(float4*)&smem[(4 * 512 + slot) * 4] = v; }
    __syncthreads();
    // everyone: sum si across groups -> invI
    float4 sv = {0.f, 0.f, 0.f, 0.f};
#pragma unroll
    for (int g = 0; g < NW; ++g) {
        float4 v = *(const float4*)&smem[(4 * 512 + g * 64 + lane) * 4];
        sv.x += v.x; sv.y += v.y; sv.z += v.z; sv.w += v.w;
    }
    float4 vI;
    vI.x = 1.f / (sqrtf(sv.x) + EPSV);
    vI.y = 1.f / (sqrtf(sv.y) + EPSV);
    vI.z = 1.f / (sqrtf(sv.z) + EPSV);
    vI.w = 1.f / (sqrtf(sv.w) + EPSV);

    const int y  = y0 + ty;
    const int xb = x0 + 4 * xc;
    const float* wmRow = &smem[OFF_INVM + ty * MCOLS + 4 * xc + 3];
    float* ocB = out + (size_t)(n * 81 + iOff * RADIUS) * HW + (size_t)y * W_ + xb;

    if (w < 4) {                           // waves 0..3 store j = w
        const int j = w;
        float4 s = {0.f, 0.f, 0.f, 0.f};
#pragma unroll
        for (int g = 0; g < NW; ++g) {
            float4 v = *(const float4*)&smem[(j * 512 + g * 64 + lane) * 4];
            s.x += v.x; s.y += v.y; s.z += v.z; s.w += v.w;
        }
        float4 vd, vc;
        vd.x = s.x * vI.x; vd.y = s.y * vI.y; vd.z = s.z * vI.z; vd.w = s.w * vI.w;
        vc.x = 1.f - vd.x * wmRow[j + 0];
        vc.y = 1.f - vd.y * wmRow[j + 1];
        vc.z = 1.f - vd.z * wmRow[j + 2];
        vc.w = 1.f - vd.w * wmRow[j + 3];
        *(float4*)(ocB + (size_t)j * HW) = vc;
        *(float4*)(ocB + OUT1 + (size_t)j * HW) = vd;
    }
    __syncthreads();
    // ---- half 2: j=4..8 ----
#pragma unroll
    for (int q = 0; q < 5; ++q) {
        float4 v = {acc[0][q + 4], acc[1][q + 4], acc[2][q + 4], acc[3][q + 4]};
        *(float4*)&smem[(q * 512 + slot) * 4] = v;
    }
    __syncthreads();
    if (w >= 4) {                          // waves 4..7 store j = w
        const int j = w;
        float4 s = {0.f, 0.f, 0.f, 0.f};
#pragma unroll
        for (int g = 0; g < NW; ++g) {
            float4 v = *(const float4*)&smem[((j - 4) * 512 + g * 64 + lane) * 4];
            s.x += v.x; s.y += v.y; s.z += v.z; s.w += v.w;
        }
        float4 vd, vc;
        vd.x = s.x * vI.x; vd.y = s.y * vI.y; vd.z = s.z * vI.z; vd.w = s.w * vI.w;
        vc.x = 1.f - vd.x * wmRow[j + 0];
        vc.y = 1.f - vd.y * wmRow[j + 1];
        vc.z = 1.f - vd.z * wmRow[j + 2];
        vc.w = 1.f - vd.w * wmRow[j + 3];
        *(float4*)(ocB + (size_t)j * HW) = vc;
        *(float4*)(ocB + OUT1 + (size_t)j * HW) = vd;
    }
    if (w == 0) {                          // wave 0 also stores j = 8
        const int j = 8;
        float4 s = {0.f, 0.f, 0.f, 0.f};
#pragma unroll
        for (int g = 0; g < NW; ++g) {
            float4 v = *(const float4*)&smem[(4 * 512 + g * 64 + lane) * 4];
            s.x += v.x; s.y += v.y; s.z += v.z; s.w += v.w;
        }
        float4 vd, vc;
        vd.x = s.x * vI.x; vd.y = s.y * vI.y; vd.z = s.z * vI.z; vd.w = s.w * vI.w;
        vc.x = 1.f - vd.x * wmRow[j + 0];
        vc.y = 1.f - vd.y * wmRow[j + 1];
        vc.z = 1.f - vd.z * wmRow[j + 2];
        vc.w = 1.f - vd.w * wmRow[j + 3];
        *(float4*)(ocB + (size_t)j * HW) = vc;
        *(float4*)(ocB + OUT1 + (size_t)j * HW) = vd;
    }
}

extern "C" void kernel_launch(void* const* d_in, const int* in_sizes, int n_in,
                              void* d_out, int out_size, void* d_ws, size_t ws_size,
                              hipStream_t stream) {
    const float* img = (const float*)d_in[0];
    const float* mp  = (const float*)d_in[1];
    float* out  = (float*)d_out;
    float* invM = (float*)d_ws;                   // N_*HW floats

    norms_kernel<<<(N_ * HW / 4) / 8, 64, 0, stream>>>(mp, invM);

    dim3 grid(W_ / XT, H_ / YT, N_ * RADIUS);     // 3 x 32 x 18 = 1728 blocks
    corr_kernel<<<grid, NT, 0, stream>>>(img, mp, invM, out);
}

// Round 15
// 40.981 us; speedup vs baseline: 1.8121x; 1.3013x over previous
//
#include <hip/hip_runtime.h>
#include <math.h>

namespace {
constexpr int RADIUS = 9;
constexpr float EPSV = 1e-5f;
constexpr int N_ = 2, C_ = 64, H_ = 128, W_ = 192;
constexpr int HW  = H_ * W_;            // 24576
constexpr int CHW = C_ * HW;
constexpr size_t OUT1 = (size_t)N_ * 81 * HW;

constexpr int XT = 64, YT = 4;          // spatial tile; i fully in grid.z
constexpr int NT = 256;                 // 4 waves; wave = channel-group of 16
constexpr int NW = 4;
constexpr int ROUNDS = 16;              // 1 channel / wave / round
constexpr int MROWS = 4;
constexpr int NCH = 19;                 // invM halo chunks per row
constexpr int MCOLS = 76;
constexpr int MAP_SLOTS = MROWS * NCH;  // 76
// LDS: epilogue reduce overlay (5 * 256 slots * 4 floats) + invM halo
constexpr int OFF_INVM = 5 * 256 * 4;   // 5120
constexpr int LDS_F = OFF_INVM + MROWS * MCOLS;   // 5424 floats = 21696 B
}

// ---------------------------------------------------------------------------
// Kernel 1: invM (map channel-norms). 8-way c-split, 64-thread blocks.
// ---------------------------------------------------------------------------
__global__ __launch_bounds__(64)
void norms_kernel(const float* __restrict__ mp,
                  float* __restrict__ invM) {
    __shared__ float4 sM[8][8];
    const int tid = threadIdx.x;
    const int cg = tid >> 3;
    const int s  = tid & 7;
    const int q4 = blockIdx.x * 8 + s;
    const int n = q4 / (HW / 4);
    const int pix = (q4 - n * (HW / 4)) * 4;
    const float* pm = mp + (size_t)n * CHW + pix;

    float4 sm = {0.f, 0.f, 0.f, 0.f};
#pragma unroll
    for (int cc = 0; cc < 8; ++cc) {
        float4 b = *(const float4*)(pm + (size_t)(cg * 8 + cc) * HW);
        sm.x = fmaf(b.x, b.x, sm.x); sm.y = fmaf(b.y, b.y, sm.y);
        sm.z = fmaf(b.z, b.z, sm.z); sm.w = fmaf(b.w, b.w, sm.w);
    }
    sM[cg][s] = sm;
    __syncthreads();
    if (tid < 8) {
        float4 b = sM[0][tid];
#pragma unroll
        for (int g = 1; g < 8; ++g) {
            float4 v = sM[g][tid];
            b.x += v.x; b.y += v.y; b.z += v.z; b.w += v.w;
        }
        float4 vm;
        vm.x = 1.f / (sqrtf(b.x) + EPSV); vm.y = 1.f / (sqrtf(b.y) + EPSV);
        vm.z = 1.f / (sqrtf(b.z) + EPSV); vm.w = 1.f / (sqrtf(b.w) + EPSV);
        *(float4*)(invM + (size_t)n * HW + pix) = vm;
    }
}

// ---------------------------------------------------------------------------
// Kernel 2: raw correlation + inline img-norm. NO LDS in the main loop:
// each lane reads its 16-float map window directly from global (L1/L2-hit,
// coalesced overlapping dwordx4) and img from global. Left-edge replicate
// via in-register splat; y-clamp folded into the per-lane row pointer.
//   dotRaw[p,(i,j)] = sum_c map[c, clamp(p+(i,j)-9)] * img[c, p]
//   out_diss = invI[p]*dotRaw ;  out_cos = 1 - invM[p']*out_diss
// Block: 256 thr = 4 waves; wave = 16 channels; 16 rounds of 1 channel.
// ---------------------------------------------------------------------------
__global__ __launch_bounds__(NT)
void corr_kernel(const float* __restrict__ img,
                 const float* __restrict__ mp,
                 const float* __restrict__ invMg,
                 float* __restrict__ out) {
    __shared__ float smem[LDS_F];

    const int bz = blockIdx.z;             // n*9 + i
    const int n    = bz / RADIUS;
    const int iOff = bz - n * RADIUS;
    const int y0 = blockIdx.y * YT;
    const int x0 = blockIdx.x * XT;
    const int tid = threadIdx.x;
    const int w    = tid >> 6;             // wave = channel group (16 ch)
    const int lane = tid & 63;
    const int ty = lane >> 4;              // 0..3
    const int xc = lane & 15;              // 0..15
    const int ch0 = w * 16;

    const float* imgN = img + (size_t)n * CHW;
    const float* mapN = mp  + (size_t)n * CHW;

    // ---- invM halo (76 float4; epilogue-only, synced by epilogue barrier) ----
    if (tid < MAP_SLOTS) {
        int r = tid / NCH, k = tid - r * NCH;
        int gy = min(max(y0 + iOff - RADIUS + r, 0), H_ - 1);
        int gxs = x0 - 12 + 4 * k;
        const float* src = invMg + n * HW + (size_t)gy * W_;
        float4 v;
        if (gxs >= 0) v = *(const float4*)(src + gxs);
        else { float s0 = src[0]; v.x = s0; v.y = s0; v.z = s0; v.w = s0; }
        *(float4*)&smem[OFF_INVM + r * MCOLS + 4 * k] = v;
    }

    // ---- per-lane direct-read descriptors ----
    // map row for this lane (y-clamp folded in; one row per lane)
    const int gy = min(max(y0 + ty + iOff - RADIUS, 0), H_ - 1);
    const float* rowp = mapN + (size_t)ch0 * HW + (size_t)gy * W_;
    // 4 chunks at x = x0+4xc-12+4d, d=0..3; left-OOB -> clamp base, splat later
    bool bc[4]; const float* pd[4];
#pragma unroll
    for (int d = 0; d < 4; ++d) {
        int gx = x0 + 4 * xc - 12 + 4 * d;
        bc[d] = (gx < 0);
        pd[d] = rowp + (gx < 0 ? 0 : gx);
    }
    const float* pI = imgN + (size_t)ch0 * HW + (size_t)(y0 + ty) * W_ + x0 + 4 * xc;

    float acc[4][RADIUS];
#pragma unroll
    for (int p = 0; p < 4; ++p)
#pragma unroll
        for (int j = 0; j < RADIUS; ++j) acc[p][j] = 0.f;
    float si[4] = {0.f, 0.f, 0.f, 0.f};

    // ---- main loop: pure register dataflow, no LDS, no barriers ----
#pragma unroll 4
    for (int ri = 0; ri < ROUNDS; ++ri) {
        const size_t off = (size_t)ri * HW;
        float wreg[16];
        *(float4*)&wreg[0]  = *(const float4*)(pd[0] + off);
        *(float4*)&wreg[4]  = *(const float4*)(pd[1] + off);
        *(float4*)&wreg[8]  = *(const float4*)(pd[2] + off);
        *(float4*)&wreg[12] = *(const float4*)(pd[3] + off);
        const float4 a4 = *(const float4*)(pI + off);
#pragma unroll
        for (int d = 0; d < 3; ++d) {      // left-edge replicate splat (in-reg)
            if (bc[d]) { wreg[4*d+1] = wreg[4*d]; wreg[4*d+2] = wreg[4*d]; wreg[4*d+3] = wreg[4*d]; }
        }
        const float a[4] = {a4.x, a4.y, a4.z, a4.w};
        si[0] = fmaf(a[0], a[0], si[0]);
        si[1] = fmaf(a[1], a[1], si[1]);
        si[2] = fmaf(a[2], a[2], si[2]);
        si[3] = fmaf(a[3], a[3], si[3]);
#pragma unroll
        for (int p = 0; p < 4; ++p)
#pragma unroll
            for (int j = 0; j < RADIUS; ++j)
                acc[p][j] = fmaf(wreg[p + j + 3], a[p], acc[p][j]);
    }

    // ==== epilogue: 4-way cross-wave reduce, SoA float4 layout ====
    __syncthreads();                       // invM halo ready; LDS free
    const int slot = tid;                  // 0..255
    // ---- half 1: j=0..3 + si ----
#pragma unroll
    for (int q = 0; q < 4; ++q) {
        float4 v = {acc[0][q], acc[1][q], acc[2][q], acc[3][q]};
        *(float4*)&smem[(q * 256 + slot) * 4] = v;
    }
    { float4 v = {si[0], si[1], si[2], si[3]}; *(float4*)&smem[(4 * 256 + slot) * 4] = v; }
    __syncthreads();
    // everyone: sum si across groups -> invI
    float4 sv = {0.f, 0.f, 0.f, 0.f};
#pragma unroll
    for (int g = 0; g < NW; ++g) {
        float4 v = *(const float4*)&smem[(4 * 256 + g * 64 + lane) * 4];
        sv.x += v.x; sv.y += v.y; sv.z += v.z; sv.w += v.w;
    }
    float4 vI;
    vI.x = 1.f / (sqrtf(sv.x) + EPSV);
    vI.y = 1.f / (sqrtf(sv.y) + EPSV);
    vI.z = 1.f / (sqrtf(sv.z) + EPSV);
    vI.w = 1.f / (sqrtf(sv.w) + EPSV);

    const int y  = y0 + ty;
    const int xb = x0 + 4 * xc;
    const float* wmRow = &smem[OFF_INVM + ty * MCOLS + 4 * xc + 3];
    float* ocB = out + (size_t)(n * 81 + iOff * RADIUS) * HW + (size_t)y * W_ + xb;

    {   // waves 0..3 store j = w
        const int j = w;
        float4 s = {0.f, 0.f, 0.f, 0.f};
#pragma unroll
        for (int g = 0; g < NW; ++g) {
            float4 v = *(const float4*)&smem[(j * 256 + g * 64 + lane) * 4];
            s.x += v.x; s.y += v.y; s.z += v.z; s.w += v.w;
        }
        float4 vd, vc;
        vd.x = s.x * vI.x; vd.y = s.y * vI.y; vd.z = s.z * vI.z; vd.w = s.w * vI.w;
        vc.x = 1.f - vd.x * wmRow[j + 0];
        vc.y = 1.f - vd.y * wmRow[j + 1];
        vc.z = 1.f - vd.z * wmRow[j + 2];
        vc.w = 1.f - vd.w * wmRow[j + 3];
        *(float4*)(ocB + (size_t)j * HW) = vc;
        *(float4*)(ocB + OUT1 + (size_t)j * HW) = vd;
    }
    __syncthreads();
    // ---- half 2: j=4..8 ----
#pragma unroll
    for (int q = 0; q < 5; ++q) {
        float4 v = {acc[0][q + 4], acc[1][q + 4], acc[2][q + 4], acc[3][q + 4]};
        *(float4*)&smem[(q * 256 + slot) * 4] = v;
    }
    __syncthreads();
    {   // waves 0..3 store j = 4 + w
        const int j = 4 + w;
        float4 s = {0.f, 0.f, 0.f, 0.f};
#pragma unroll
        for (int g = 0; g < NW; ++g) {
            float4 v = *(const float4*)&smem[((j - 4) * 256 + g * 64 + lane) * 4];
            s.x += v.x; s.y += v.y; s.z += v.z; s.w += v.w;
        }
        float4 vd, vc;
        vd.x = s.x * vI.x; vd.y = s.y * vI.y; vd.z = s.z * vI.z; vd.w = s.w * vI.w;
        vc.x = 1.f - vd.x * wmRow[j + 0];
        vc.y = 1.f - vd.y * wmRow[j + 1];
        vc.z = 1.f - vd.z * wmRow[j + 2];
        vc.w = 1.f - vd.w * wmRow[j + 3];
        *(float4*)(ocB + (size_t)j * HW) = vc;
        *(float4*)(ocB + OUT1 + (size_t)j * HW) = vd;
    }
    if (w == 0) {                          // wave 0 also stores j = 8
        const int j = 8;
        float4 s = {0.f, 0.f, 0.f, 0.f};
#pragma unroll
        for (int g = 0; g < NW; ++g) {
            float4 v = *(const float4*)&smem[(4 * 256 + g * 64 + lane) * 4];
            s.x += v.x; s.y += v.y; s.z += v.z; s.w += v.w;
        }
        float4 vd, vc;
        vd.x = s.x * vI.x; vd.y = s.y * vI.y; vd.z = s.z * vI.z; vd.w = s.w * vI.w;
        vc.x = 1.f - vd.x * wmRow[j + 0];
        vc.y = 1.f - vd.y * wmRow[j + 1];
        vc.z = 1.f - vd.z * wmRow[j + 2];
        vc.w = 1.f - vd.w * wmRow[j + 3];
        *(float4*)(ocB + (size_t)j * HW) = vc;
        *(float4*)(ocB + OUT1 + (size_t)j * HW) = vd;
    }
}

extern "C" void kernel_launch(void* const* d_in, const int* in_sizes, int n_in,
                              void* d_out, int out_size, void* d_ws, size_t ws_size,
                              hipStream_t stream) {
    const float* img = (const float*)d_in[0];
    const float* mp  = (const float*)d_in[1];
    float* out  = (float*)d_out;
    float* invM = (float*)d_ws;                   // N_*HW floats

    norms_kernel<<<(N_ * HW / 4) / 8, 64, 0, stream>>>(mp, invM);

    dim3 grid(W_ / XT, H_ / YT, N_ * RADIUS);     // 3 x 32 x 18 = 1728 blocks
    corr_kernel<<<grid, NT, 0, stream>>>(img, mp, invM, out);
}